// Round 1
// baseline (348.025 us; speedup 1.0000x reference)
//
#include <hip/hip_runtime.h>
#include <math.h>

#define N_NODES 1000
#define E_EDGES 64000
#define NB1     1024          // dense1 partial blocks
#define ROWS1   500           // 512000 / NB1 rows per block

// ---------------- graph preprocessing ----------------

__global__ void k_init_deg(int* deg){
    int i = blockIdx.x * blockDim.x + threadIdx.x;
    if (i < N_NODES) deg[i] = 1;            // self loop
}

__global__ void k_count(const int* __restrict__ dst, int* deg){
    int e = blockIdx.x * blockDim.x + threadIdx.x;
    if (e < E_EDGES) atomicAdd(&deg[dst[e]], 1);
}

__global__ __launch_bounds__(1024)
void k_scan(const int* __restrict__ deg, int* row_ptr, int* cursor,
            int* csr_src, float* dinv){
    __shared__ int s[1024];
    int t = threadIdx.x;
    int v = (t < N_NODES) ? deg[t] : 0;
    s[t] = v;
    __syncthreads();
    for (int off = 1; off < 1024; off <<= 1){
        int a = (t >= off) ? s[t - off] : 0;
        __syncthreads();
        s[t] += a;
        __syncthreads();
    }
    int excl = s[t] - v;                     // exclusive prefix
    if (t < N_NODES){
        row_ptr[t] = excl;
        cursor[t]  = excl + 1;               // slot 0 reserved for self loop
        csr_src[excl] = t;
        dinv[t] = rsqrtf((float)v);
    }
    if (t == 1023) row_ptr[N_NODES] = s[1023];
}

__global__ void k_fill(const int* __restrict__ srcs, const int* __restrict__ dsts,
                       int* cursor, int* csr_src){
    int e = blockIdx.x * blockDim.x + threadIdx.x;
    if (e < E_EDGES){
        int pos = atomicAdd(&cursor[dsts[e]], 1);
        csr_src[pos] = srcs[e];
    }
}

// ---------------- GCN layer ----------------
// hs[i][j] = dinv[i] * sum_k X[i][k] * W[k][j]    X:[1000][K] W:[K][512]
template<int K>
__global__ __launch_bounds__(512)
void k_gemm_scale(const float* __restrict__ X, const float* __restrict__ W,
                  const float* __restrict__ dinv, float* __restrict__ hs){
    __shared__ float xs[8][K];
    int t = threadIdx.x;
    int row0 = blockIdx.x * 8;
    for (int idx = t; idx < 8 * K; idx += 512){
        int r = idx / K, k = idx - r * K;
        xs[r][k] = X[(row0 + r) * K + k];
    }
    __syncthreads();
    float acc[8] = {0.f,0.f,0.f,0.f,0.f,0.f,0.f,0.f};
    #pragma unroll 4
    for (int k = 0; k < K; ++k){
        float w = W[k * 512 + t];
        #pragma unroll
        for (int r = 0; r < 8; ++r) acc[r] += xs[r][k] * w;
    }
    #pragma unroll
    for (int r = 0; r < 8; ++r){
        int row = row0 + r;
        hs[row * 512 + t] = acc[r] * dinv[row];
    }
}

// out[d][f] = tanh(dinv[d] * sum_{e in CSR[d]} hs[src_e][f] + b[f])
__global__ __launch_bounds__(512)
void k_agg(const float* __restrict__ hs, const int* __restrict__ row_ptr,
           const int* __restrict__ csr_src, const float* __restrict__ dinv,
           const float* __restrict__ b, float* __restrict__ out){
    int d = blockIdx.x;
    int f = threadIdx.x;
    int beg = row_ptr[d], end = row_ptr[d + 1];
    float s = 0.f;
    int idx = beg;
    for (; idx + 4 <= end; idx += 4){
        int s0 = csr_src[idx + 0], s1 = csr_src[idx + 1];
        int s2 = csr_src[idx + 2], s3 = csr_src[idx + 3];
        float v0 = hs[s0 * 512 + f], v1 = hs[s1 * 512 + f];
        float v2 = hs[s2 * 512 + f], v3 = hs[s3 * 512 + f];
        s += v0 + v1 + v2 + v3;
    }
    for (; idx < end; ++idx) s += hs[csr_src[idx] * 512 + f];
    out[d * 512 + f] = tanhf(dinv[d] * s + b[f]);
}

// ---------------- dense head ----------------
// partial[b][j] = sum over block b's row chunk of f[i]*Wd1[i][j]
__global__ __launch_bounds__(256)
void k_dense1(const float* __restrict__ f, const float* __restrict__ W,
              float* __restrict__ partial){
    int t  = threadIdx.x;
    int r  = t >> 6;                 // 0..3 (wave id -> f[i] wave-uniform)
    int c4 = t & 63;                 // 64 groups x float4 = 256 cols
    int base = blockIdx.x * ROWS1 + r;
    float4 acc = {0.f,0.f,0.f,0.f};
    #pragma unroll 4
    for (int it = 0; it < ROWS1 / 4; ++it){
        int i = base + it * 4;
        float fv = f[i];
        const float4 w = *reinterpret_cast<const float4*>(W + (size_t)i * 256 + c4 * 4);
        acc.x += fv * w.x; acc.y += fv * w.y;
        acc.z += fv * w.z; acc.w += fv * w.w;
    }
    __shared__ float4 red[256];
    red[t] = acc;
    __syncthreads();
    if (t < 64){
        float4 a = red[t], b4 = red[t + 64], c = red[t + 128], d4 = red[t + 192];
        float4 o;
        o.x = a.x + b4.x + c.x + d4.x;
        o.y = a.y + b4.y + c.y + d4.y;
        o.z = a.z + b4.z + c.z + d4.z;
        o.w = a.w + b4.w + c.w + d4.w;
        *reinterpret_cast<float4*>(partial + blockIdx.x * 256 + t * 4) = o;
    }
}

__global__ __launch_bounds__(256)
void k_dense1_reduce(const float* __restrict__ partial, const float* __restrict__ bias,
                     float* __restrict__ y){
    int j = blockIdx.x;
    int t = threadIdx.x;
    float s = 0.f;
    for (int b = t; b < NB1; b += 256) s += partial[b * 256 + j];
    __shared__ float red[256];
    red[t] = s;
    __syncthreads();
    for (int off = 128; off > 0; off >>= 1){
        if (t < off) red[t] += red[t + off];
        __syncthreads();
    }
    if (t == 0){
        float v = red[0] + bias[j];
        y[j] = v > 0.f ? v : 0.1f * v;
    }
}

__global__ __launch_bounds__(64)
void k_dense_small(const float* __restrict__ yin, const float* __restrict__ W,
                   const float* __restrict__ bias, float* __restrict__ yout){
    __shared__ float ys[256];
    int t = threadIdx.x;
    int col = blockIdx.x * 64 + t;
    for (int i = t; i < 256; i += 64) ys[i] = yin[i];
    __syncthreads();
    float acc = 0.f;
    #pragma unroll 8
    for (int i = 0; i < 256; ++i) acc += ys[i] * W[i * 256 + col];
    float v = acc + bias[col];
    yout[col] = v > 0.f ? v : 0.1f * v;
}

__global__ __launch_bounds__(256)
void k_final(const float* __restrict__ y3, const float* __restrict__ w,
             const float* __restrict__ b, float* __restrict__ out){
    int t = threadIdx.x;
    __shared__ float red[256];
    red[t] = y3[t] * w[t];
    __syncthreads();
    for (int off = 128; off > 0; off >>= 1){
        if (t < off) red[t] += red[t + off];
        __syncthreads();
    }
    if (t == 0) out[0] = red[0] + b[0];
}

// ---------------- launch ----------------

extern "C" void kernel_launch(void* const* d_in, const int* in_sizes, int n_in,
                              void* d_out, int out_size, void* d_ws, size_t ws_size,
                              hipStream_t stream) {
    const float* x   = (const float*)d_in[0];
    const int*   ei  = (const int*)  d_in[1];
    const float* W1  = (const float*)d_in[2];  const float* b1  = (const float*)d_in[3];
    const float* W2  = (const float*)d_in[4];  const float* b2  = (const float*)d_in[5];
    const float* W3  = (const float*)d_in[6];  const float* b3  = (const float*)d_in[7];
    const float* Wd1 = (const float*)d_in[8];  const float* bd1 = (const float*)d_in[9];
    const float* Wd2 = (const float*)d_in[10]; const float* bd2 = (const float*)d_in[11];
    const float* Wd3 = (const float*)d_in[12]; const float* bd3 = (const float*)d_in[13];
    const float* Wd4 = (const float*)d_in[14]; const float* bd4 = (const float*)d_in[15];
    float* out = (float*)d_out;

    const int* src = ei;
    const int* dst = ei + E_EDGES;

    // workspace layout (bytes)
    char* ws = (char*)d_ws;
    int*   deg     = (int*)  (ws + 0);
    int*   row_ptr = (int*)  (ws + 4096);
    int*   cursor  = (int*)  (ws + 8192);
    float* dinv    = (float*)(ws + 12288);
    int*   csr_src = (int*)  (ws + 16384);                 // 65000 ints
    float* hs      = (float*)(ws + 16384 + 262144);        // 2 MB
    float* hA      = (float*)(ws + 16384 + 262144 + 2097152);
    float* partial = (float*)(ws + 16384 + 262144 + 2*2097152);  // 1 MB
    float* y1      = (float*)(ws + 16384 + 262144 + 2*2097152 + 1048576);
    float* y2      = y1 + 256;
    float* y3      = y2 + 256;

    k_init_deg<<<4, 256, 0, stream>>>(deg);
    k_count<<<E_EDGES / 256, 256, 0, stream>>>(dst, deg);
    k_scan<<<1, 1024, 0, stream>>>(deg, row_ptr, cursor, csr_src, dinv);
    k_fill<<<E_EDGES / 256, 256, 0, stream>>>(src, dst, cursor, csr_src);

    // layer 1
    k_gemm_scale<128><<<125, 512, 0, stream>>>(x, W1, dinv, hs);
    k_agg<<<N_NODES, 512, 0, stream>>>(hs, row_ptr, csr_src, dinv, b1, hA);
    // layer 2
    k_gemm_scale<512><<<125, 512, 0, stream>>>(hA, W2, dinv, hs);
    k_agg<<<N_NODES, 512, 0, stream>>>(hs, row_ptr, csr_src, dinv, b2, hA);
    // layer 3
    k_gemm_scale<512><<<125, 512, 0, stream>>>(hA, W3, dinv, hs);
    k_agg<<<N_NODES, 512, 0, stream>>>(hs, row_ptr, csr_src, dinv, b3, hA);

    // dense head
    k_dense1<<<NB1, 256, 0, stream>>>(hA, Wd1, partial);
    k_dense1_reduce<<<256, 256, 0, stream>>>(partial, bd1, y1);
    k_dense_small<<<4, 64, 0, stream>>>(y1, Wd2, bd2, y2);
    k_dense_small<<<4, 64, 0, stream>>>(y2, Wd3, bd3, y3);
    k_final<<<1, 256, 0, stream>>>(y3, Wd4, bd4, out);
}